// Round 5
// baseline (4348.680 us; speedup 1.0000x reference)
//
#include <hip/hip_runtime.h>
#include <hip/hip_bf16.h>
#include <stdint.h>

#define F_DIM 512
#define C_DIM 512
#define K3    1536   // 3 * F_DIM
#define NT    24     // K3 / 64
#define NT2   12

typedef _Float16 f16x8 __attribute__((ext_vector_type(8)));
typedef float    f32x4 __attribute__((ext_vector_type(4)));

__device__ __forceinline__ float rho_of(int p, int sb) {
    int d = sb - 1; if (d < 1) d = 1;
    return (float)(p - 1) / (float)d;
}

// 2-way fp16 split with exact pow2 plane scaling: v ~= h + m*2^-11
// (m plane scaled into normal fp16 range; residual ~2^-24*|v|)
__device__ __forceinline__ void split2s(float v, _Float16& h, _Float16& m) {
    h = (_Float16)v;
    float r1 = v - (float)h;          // exact
    m = (_Float16)(r1 * 2048.0f);     // scale exact, one rounding
}

// ---------------- CSR build ----------------
__global__ void k_count(const int* __restrict__ parent, int* __restrict__ counts, int n) {
    int c = blockIdx.x * 256 + threadIdx.x;
    if (c >= 1 && c < n) atomicAdd(&counts[parent[c]], 1);
}

__device__ __forceinline__ int blockScanIncl(int v, int* sm) {
    int lane = threadIdx.x & 63;
    int w = threadIdx.x >> 6;
    #pragma unroll
    for (int d = 1; d < 64; d <<= 1) {
        int t = __shfl_up(v, d, 64);
        if (lane >= d) v += t;
    }
    if (lane == 63) sm[w] = v;
    __syncthreads();
    if (threadIdx.x < 64) {
        int s = (threadIdx.x < 16) ? sm[threadIdx.x] : 0;
        #pragma unroll
        for (int d = 1; d < 16; d <<= 1) {
            int t = __shfl_up(s, d, 64);
            if (lane >= d) s += t;
        }
        if (threadIdx.x < 16) sm[threadIdx.x] = s;
    }
    __syncthreads();
    return v + (w > 0 ? sm[w - 1] : 0);
}

__global__ void k_scan1(const int* __restrict__ counts, int* __restrict__ starts,
                        int* __restrict__ bsums, int n) {
    __shared__ int sm[16];
    int i = blockIdx.x * 1024 + threadIdx.x;
    int v = (i < n) ? counts[i] : 0;
    int incl = blockScanIncl(v, sm);
    if (i < n) starts[i] = incl - v;
    if (threadIdx.x == 1023) bsums[blockIdx.x] = incl;
}

__global__ void k_scan2(int* __restrict__ bsums, int nb) {
    __shared__ int sm[16];
    int v = ((int)threadIdx.x < nb) ? bsums[threadIdx.x] : 0;
    int incl = blockScanIncl(v, sm);
    if ((int)threadIdx.x < nb) bsums[threadIdx.x] = incl - v;  // exclusive
}

__global__ void k_scan3(int* __restrict__ starts, const int* __restrict__ bsums, int n) {
    int i = blockIdx.x * 1024 + threadIdx.x;
    if (i < n) starts[i] += bsums[blockIdx.x];
}

__global__ void k_fill(const int* __restrict__ parent, const int* __restrict__ pos,
                       const int* __restrict__ starts, int* __restrict__ childlist, int n) {
    int c = blockIdx.x * 256 + threadIdx.x;
    if (c >= 1 && c < n) childlist[starts[parent[c]] + pos[c]] = c;
}

// ---------------- B concat + 2-way split:  B[j][sec*512+f], sec: 0=Wt 1=Wl 2=Wr
__global__ void k_bcat(const float* __restrict__ Wt, const float* __restrict__ Wl,
                       const float* __restrict__ Wr,
                       _Float16* __restrict__ Bh, _Float16* __restrict__ Bm) {
    int i = blockIdx.x * 256 + threadIdx.x;
    if (i >= C_DIM * K3) return;
    int j = i / K3, kk = i - j * K3;
    int sec = kk >> 9, f = kk & 511;
    const float* W = (sec == 0) ? Wt : ((sec == 1) ? Wl : Wr);
    float v = W[j * F_DIM + f];
    _Float16 h, m;
    split2s(v, h, m);
    Bh[i] = h; Bm[i] = m;
}

// ---------------- aggregation: one wave per node.
// S0 = sum of x over {self + children}, S1 = sum of rho*x.
// A row = [ t*S0 | u*S0 - u*u*S1 | u*S1 ]  -> 2-way split planes.
__global__ __launch_bounds__(256)
void k_agg(const float* __restrict__ x, const int* __restrict__ level,
           const int* __restrict__ pos, const int* __restrict__ sib,
           const int* __restrict__ starts, const int* __restrict__ counts,
           const int* __restrict__ childlist,
           _Float16* __restrict__ Ah, _Float16* __restrict__ Am,
           int node0, int cnt) {
    int lane = threadIdx.x & 63;
    int gw = (blockIdx.x * 256 + threadIdx.x) >> 6;
    int nW = (gridDim.x * 256) >> 6;
    for (int i = gw; i < cnt; i += nW) {
        int s = node0 + i;
        float t = 0.5f * (float)level[s];
        float u = 1.0f - t;
        float u2 = u * u;
        float s0[8], s1[8];
        #pragma unroll
        for (int j = 0; j < 8; ++j) { s0[j] = 0.f; s1[j] = 0.f; }
        {
            float r = rho_of(pos[s], sib[s]);
            const float4* xp = (const float4*)(x + (size_t)s * F_DIM) + lane * 2;
            float4 a = xp[0], b = xp[1];
            float vv[8] = {a.x, a.y, a.z, a.w, b.x, b.y, b.z, b.w};
            #pragma unroll
            for (int j = 0; j < 8; ++j) { s0[j] += vv[j]; s1[j] = fmaf(r, vv[j], s1[j]); }
        }
        int cs = starts[s], ne = counts[s];
        for (int e = 0; e < ne; ++e) {
            int c = childlist[cs + e];
            float r = rho_of(pos[c], sib[c]);
            const float4* xp = (const float4*)(x + (size_t)c * F_DIM) + lane * 2;
            float4 a = xp[0], b = xp[1];
            float vv[8] = {a.x, a.y, a.z, a.w, b.x, b.y, b.z, b.w};
            #pragma unroll
            for (int j = 0; j < 8; ++j) { s0[j] += vv[j]; s1[j] = fmaf(r, vv[j], s1[j]); }
        }
        f16x8 ph[3], pm[3];
        #pragma unroll
        for (int j = 0; j < 8; ++j) {
            float a0 = t * s0[j];
            float a1 = fmaf(-u2, s1[j], u * s0[j]);
            float a2 = u * s1[j];
            _Float16 h, m;
            split2s(a0, h, m); ph[0][j] = h; pm[0][j] = m;
            split2s(a1, h, m); ph[1][j] = h; pm[1][j] = m;
            split2s(a2, h, m); ph[2][j] = h; pm[2][j] = m;
        }
        size_t rb = (size_t)i * K3 + (size_t)(lane * 8);
        #pragma unroll
        for (int sec = 0; sec < 3; ++sec) {
            *(f16x8*)(Ah + rb + sec * 512) = ph[sec];
            *(f16x8*)(Am + rb + sec * 512) = pm[sec];
        }
    }
}

// ---------------- GEMM: out = tanh(A(M x 1536) * Bcat^T + (1+nc)*bias)
// fp16 2-plane x 2-plane, 3 products (hh -> accH0/accH1 by K-half; hm+mh -> accR1).
// 512 threads = 8 waves (2x4), wave tile 64x32, block tile 128x128, BK=64.
// m97 SINGLE-BUFFER structure: 4 planes x 16KB = 64KB LDS -> 2 blocks/CU
// (16 waves/CU). __syncthreads' vmcnt(0) drain is hidden by the co-resident
// block (m114 implicit overlap) — this beat explicit dbuf at 128^2 tile.
// LDS XOR swizzle (rule #21): linear LDS dest via global_load_lds,
// INVERSE-swizzled global source, swizzled ds_read.
__device__ __forceinline__ void stageTile(const char* gbase, _Float16* lds) {
    int tid = threadIdx.x;
    int wid = tid >> 6;
    #pragma unroll
    for (int rnd = 0; rnd < 2; ++rnd) {
        int c = rnd * 512 + tid;          // 16B chunk id within [128 rows][8 slots]
        int row = c >> 3;
        int gslot = (c & 7) ^ (row & 7);  // inverse swizzle on the SOURCE
        const void* gp = gbase + (size_t)row * (K3 * 2) + ((size_t)gslot << 4);
        _Float16* lp = lds + (size_t)(rnd * 512 + wid * 64) * 8;  // wave-uniform base
        __builtin_amdgcn_global_load_lds(
            (const __attribute__((address_space(1))) unsigned int*)gp,
            (__attribute__((address_space(3))) unsigned int*)lp, 16, 0, 0);
    }
}

__device__ __forceinline__ f32x4 mfma16(f16x8 a, f16x8 b, f32x4 c) {
    return __builtin_amdgcn_mfma_f32_16x16x32_f16(a, b, c, 0, 0, 0);
}

// one K-step's compute: interleaved per-kc {frag reads, MFMA}
__device__ __forceinline__ void compute_step(
    const _Float16* cAh, const _Float16* cAm, const _Float16* cBh, const _Float16* cBm,
    int wm, int wn, int l15, int koff0, int koff1,
    f32x4 (&accH)[4][2], f32x4 (&accR1)[4][2])
{
    #pragma unroll
    for (int kc = 0; kc < 2; ++kc) {
        int ko = kc ? koff1 : koff0;
        f16x8 ah[4], am[4], bh[2], bm[2];
        #pragma unroll
        for (int ni = 0; ni < 2; ++ni) {
            int co = (wn * 32 + ni * 16 + l15) * 64;
            bh[ni] = *(const f16x8*)&cBh[co + ko];
            bm[ni] = *(const f16x8*)&cBm[co + ko];
        }
        #pragma unroll
        for (int mi = 0; mi < 4; ++mi) {
            int ro = (wm * 64 + mi * 16 + l15) * 64;
            ah[mi] = *(const f16x8*)&cAh[ro + ko];
            am[mi] = *(const f16x8*)&cAm[ro + ko];
        }
        #pragma unroll
        for (int mi = 0; mi < 4; ++mi) {
            #pragma unroll
            for (int ni = 0; ni < 2; ++ni) {
                accH[mi][ni]  = mfma16(ah[mi], bh[ni], accH[mi][ni]);
                accR1[mi][ni] = mfma16(ah[mi], bm[ni], accR1[mi][ni]);
                accR1[mi][ni] = mfma16(am[mi], bh[ni], accR1[mi][ni]);
            }
        }
    }
}

__global__ __launch_bounds__(512, 4)
void k_gemm(const _Float16* __restrict__ Ah, const _Float16* __restrict__ Am,
            const _Float16* __restrict__ Bh, const _Float16* __restrict__ Bm,
            const float* __restrict__ bias, const int* __restrict__ counts,
            float* __restrict__ out, int Mreal, int row0) {
    __shared__ __align__(16) _Float16 sAh[128 * 64];
    __shared__ __align__(16) _Float16 sAm[128 * 64];
    __shared__ __align__(16) _Float16 sBh[128 * 64];
    __shared__ __align__(16) _Float16 sBm[128 * 64];

    // bijective XCD swizzle (m204)
    int nwg = gridDim.x, bid = blockIdx.x;
    int q = nwg >> 3, r = nwg & 7;
    int xcd = bid & 7, idx = bid >> 3;
    int wg = (xcd < r ? xcd * (q + 1) : r * (q + 1) + (xcd - r) * q) + idx;
    int panel = wg >> 2, colt = wg & 3;
    int m0 = panel * 128, n0 = colt * 128;

    int lane = threadIdx.x & 63, wid = threadIdx.x >> 6;
    int wm = wid >> 2, wn = wid & 3;
    int l15 = lane & 15, lg = lane >> 4, lx = lane & 7;

    const char* gAh = (const char*)(Ah + (size_t)m0 * K3);
    const char* gAm = (const char*)(Am + (size_t)m0 * K3);
    const char* gBh = (const char*)(Bh + (size_t)n0 * K3);
    const char* gBm = (const char*)(Bm + (size_t)n0 * K3);

    f32x4 accH0[4][2] = {};
    f32x4 accH1[4][2] = {};
    f32x4 accR1[4][2] = {};

    int koff0 = ((((0 << 2) + lg) ^ lx) << 3);
    int koff1 = ((((1 << 2) + lg) ^ lx) << 3);

    for (int t = 0; t < NT; ++t) {
        size_t kb = (size_t)t * 128;     // 64 elems * 2B along K
        stageTile(gAh + kb, sAh); stageTile(gAm + kb, sAm);
        stageTile(gBh + kb, sBh); stageTile(gBm + kb, sBm);
        __syncthreads();                 // vmcnt(0) drain hidden by co-resident block

        if (t < NT2)
            compute_step(sAh, sAm, sBh, sBm, wm, wn, l15, koff0, koff1, accH0, accR1);
        else
            compute_step(sAh, sAm, sBh, sBm, wm, wn, l15, koff0, koff1, accH1, accR1);

        __syncthreads();                 // reads done -> safe to overwrite
    }

    const float S1 = 1.0f / 2048.0f;        // 2^-11

    #pragma unroll
    for (int mi = 0; mi < 4; ++mi) {
        #pragma unroll
        for (int ni = 0; ni < 2; ++ni) {
            int colL = n0 + wn * 32 + ni * 16 + l15;
            #pragma unroll
            for (int rr = 0; rr < 4; ++rr) {
                int rowL = m0 + wm * 64 + mi * 16 + lg * 4 + rr;
                if (rowL < Mreal) {
                    int g = row0 + rowL;
                    float v = (accH0[mi][ni][rr] + accH1[mi][ni][rr])
                              + accR1[mi][ni][rr] * S1
                              + (1.0f + (float)counts[g]) * bias[colL];
                    out[(size_t)g * C_DIM + colL] = tanhf(v);
                }
            }
        }
    }
}

extern "C" void kernel_launch(void* const* d_in, const int* in_sizes, int n_in,
                              void* d_out, int out_size, void* d_ws, size_t ws_size,
                              hipStream_t stream) {
    const float* x    = (const float*)d_in[0];
    const float* Wt   = (const float*)d_in[1];
    const float* Wl   = (const float*)d_in[2];
    const float* Wr   = (const float*)d_in[3];
    const float* bias = (const float*)d_in[4];
    const int* parent = (const int*)d_in[5];
    const int* level  = (const int*)d_in[6];
    const int* pos    = (const int*)d_in[7];
    const int* sib    = (const int*)d_in[8];
    const int N = in_sizes[5];
    float* out = (float*)d_out;
    (void)n_in; (void)out_size;

    char* w = (char*)d_ws;
    size_t off = 0;
    auto alloc = [&](size_t bytes) -> void* {
        void* p = w + off;
        off += (bytes + 255) & ~(size_t)255;
        return p;
    };
    int* counts    = (int*)alloc((size_t)N * 4);
    int* starts    = (int*)alloc((size_t)N * 4);
    int* childlist = (int*)alloc((size_t)N * 4);
    int* bsums     = (int*)alloc(1024 * 4);
    _Float16* Bh   = (_Float16*)alloc((size_t)C_DIM * K3 * 2);
    _Float16* Bm   = (_Float16*)alloc((size_t)C_DIM * K3 * 2);

    size_t avail = ws_size > off ? ws_size - off : 0;
    long long Npad = ((long long)N + 127) & ~127LL;
    long long chunkM = (long long)(avail / ((size_t)K3 * 2 * 2)) & ~127LL;
    if (chunkM > Npad) chunkM = Npad;
    if (chunkM < 128) chunkM = 128;
    _Float16* Ah = (_Float16*)alloc((size_t)chunkM * K3 * 2);
    _Float16* Am = (_Float16*)alloc((size_t)chunkM * K3 * 2);

    hipMemsetAsync(counts, 0, (size_t)N * 4, stream);
    int nb256 = (N + 255) / 256;
    int nb1024 = (N + 1023) / 1024;
    k_count<<<nb256, 256, 0, stream>>>(parent, counts, N);
    k_scan1<<<nb1024, 1024, 0, stream>>>(counts, starts, bsums, N);
    k_scan2<<<1, 1024, 0, stream>>>(bsums, nb1024);
    k_scan3<<<nb1024, 1024, 0, stream>>>(starts, bsums, N);
    k_fill<<<nb256, 256, 0, stream>>>(parent, pos, starts, childlist, N);
    k_bcat<<<(C_DIM * K3 + 255) / 256, 256, 0, stream>>>(Wt, Wl, Wr, Bh, Bm);

    for (long long m0 = 0; m0 < N; m0 += chunkM) {
        int mc = (int)((N - m0 < chunkM) ? (N - m0) : chunkM);
        int mcPad = (mc + 127) & ~127;
        k_agg<<<2048, 256, 0, stream>>>(x, level, pos, sib, starts, counts, childlist,
                                        Ah, Am, (int)m0, mc);
        int ntiles = (mcPad / 128) * 4;
        k_gemm<<<ntiles, 512, 0, stream>>>(Ah, Am, Bh, Bm, bias, counts,
                                           out, mc, (int)m0);
    }
}

// Round 6
// 1113.223 us; speedup vs baseline: 3.9064x; 3.9064x over previous
//
#include <hip/hip_runtime.h>
#include <hip/hip_bf16.h>
#include <stdint.h>

#define F_DIM 512
#define C_DIM 512
#define K3    1536   // 3 * F_DIM
#define NT    24     // K3 / 64
#define NT2   12

typedef _Float16 f16x8 __attribute__((ext_vector_type(8)));
typedef float    f32x4 __attribute__((ext_vector_type(4)));

__device__ __forceinline__ float rho_of(int p, int sb) {
    int d = sb - 1; if (d < 1) d = 1;
    return (float)(p - 1) / (float)d;
}

// 2-way fp16 split with exact pow2 plane scaling: v ~= h + m*2^-11
// (m plane scaled into normal fp16 range; residual ~2^-24*|v|)
__device__ __forceinline__ void split2s(float v, _Float16& h, _Float16& m) {
    h = (_Float16)v;
    float r1 = v - (float)h;          // exact
    m = (_Float16)(r1 * 2048.0f);     // scale exact, one rounding
}

// ---------------- CSR build ----------------
__global__ void k_count(const int* __restrict__ parent, int* __restrict__ counts, int n) {
    int c = blockIdx.x * 256 + threadIdx.x;
    if (c >= 1 && c < n) atomicAdd(&counts[parent[c]], 1);
}

__device__ __forceinline__ int blockScanIncl(int v, int* sm) {
    int lane = threadIdx.x & 63;
    int w = threadIdx.x >> 6;
    #pragma unroll
    for (int d = 1; d < 64; d <<= 1) {
        int t = __shfl_up(v, d, 64);
        if (lane >= d) v += t;
    }
    if (lane == 63) sm[w] = v;
    __syncthreads();
    if (threadIdx.x < 64) {
        int s = (threadIdx.x < 16) ? sm[threadIdx.x] : 0;
        #pragma unroll
        for (int d = 1; d < 16; d <<= 1) {
            int t = __shfl_up(s, d, 64);
            if (lane >= d) s += t;
        }
        if (threadIdx.x < 16) sm[threadIdx.x] = s;
    }
    __syncthreads();
    return v + (w > 0 ? sm[w - 1] : 0);
}

__global__ void k_scan1(const int* __restrict__ counts, int* __restrict__ starts,
                        int* __restrict__ bsums, int n) {
    __shared__ int sm[16];
    int i = blockIdx.x * 1024 + threadIdx.x;
    int v = (i < n) ? counts[i] : 0;
    int incl = blockScanIncl(v, sm);
    if (i < n) starts[i] = incl - v;
    if (threadIdx.x == 1023) bsums[blockIdx.x] = incl;
}

__global__ void k_scan2(int* __restrict__ bsums, int nb) {
    __shared__ int sm[16];
    int v = ((int)threadIdx.x < nb) ? bsums[threadIdx.x] : 0;
    int incl = blockScanIncl(v, sm);
    if ((int)threadIdx.x < nb) bsums[threadIdx.x] = incl - v;  // exclusive
}

__global__ void k_scan3(int* __restrict__ starts, const int* __restrict__ bsums, int n) {
    int i = blockIdx.x * 1024 + threadIdx.x;
    if (i < n) starts[i] += bsums[blockIdx.x];
}

__global__ void k_fill(const int* __restrict__ parent, const int* __restrict__ pos,
                       const int* __restrict__ starts, int* __restrict__ childlist, int n) {
    int c = blockIdx.x * 256 + threadIdx.x;
    if (c >= 1 && c < n) childlist[starts[parent[c]] + pos[c]] = c;
}

// ---------------- B concat + 2-way split:  B[j][sec*512+f], sec: 0=Wt 1=Wl 2=Wr
__global__ void k_bcat(const float* __restrict__ Wt, const float* __restrict__ Wl,
                       const float* __restrict__ Wr,
                       _Float16* __restrict__ Bh, _Float16* __restrict__ Bm) {
    int i = blockIdx.x * 256 + threadIdx.x;
    if (i >= C_DIM * K3) return;
    int j = i / K3, kk = i - j * K3;
    int sec = kk >> 9, f = kk & 511;
    const float* W = (sec == 0) ? Wt : ((sec == 1) ? Wl : Wr);
    float v = W[j * F_DIM + f];
    _Float16 h, m;
    split2s(v, h, m);
    Bh[i] = h; Bm[i] = m;
}

// ---------------- aggregation: one wave per node.
// S0 = sum of x over {self + children}, S1 = sum of rho*x.
// A row = [ t*S0 | u*S0 - u*u*S1 | u*S1 ]  -> 2-way split planes.
__global__ __launch_bounds__(256)
void k_agg(const float* __restrict__ x, const int* __restrict__ level,
           const int* __restrict__ pos, const int* __restrict__ sib,
           const int* __restrict__ starts, const int* __restrict__ counts,
           const int* __restrict__ childlist,
           _Float16* __restrict__ Ah, _Float16* __restrict__ Am,
           int node0, int cnt) {
    int lane = threadIdx.x & 63;
    int gw = (blockIdx.x * 256 + threadIdx.x) >> 6;
    int nW = (gridDim.x * 256) >> 6;
    for (int i = gw; i < cnt; i += nW) {
        int s = node0 + i;
        float t = 0.5f * (float)level[s];
        float u = 1.0f - t;
        float u2 = u * u;
        float s0[8], s1[8];
        #pragma unroll
        for (int j = 0; j < 8; ++j) { s0[j] = 0.f; s1[j] = 0.f; }
        {
            float r = rho_of(pos[s], sib[s]);
            const float4* xp = (const float4*)(x + (size_t)s * F_DIM) + lane * 2;
            float4 a = xp[0], b = xp[1];
            float vv[8] = {a.x, a.y, a.z, a.w, b.x, b.y, b.z, b.w};
            #pragma unroll
            for (int j = 0; j < 8; ++j) { s0[j] += vv[j]; s1[j] = fmaf(r, vv[j], s1[j]); }
        }
        int cs = starts[s], ne = counts[s];
        for (int e = 0; e < ne; ++e) {
            int c = childlist[cs + e];
            float r = rho_of(pos[c], sib[c]);
            const float4* xp = (const float4*)(x + (size_t)c * F_DIM) + lane * 2;
            float4 a = xp[0], b = xp[1];
            float vv[8] = {a.x, a.y, a.z, a.w, b.x, b.y, b.z, b.w};
            #pragma unroll
            for (int j = 0; j < 8; ++j) { s0[j] += vv[j]; s1[j] = fmaf(r, vv[j], s1[j]); }
        }
        f16x8 ph[3], pm[3];
        #pragma unroll
        for (int j = 0; j < 8; ++j) {
            float a0 = t * s0[j];
            float a1 = fmaf(-u2, s1[j], u * s0[j]);
            float a2 = u * s1[j];
            _Float16 h, m;
            split2s(a0, h, m); ph[0][j] = h; pm[0][j] = m;
            split2s(a1, h, m); ph[1][j] = h; pm[1][j] = m;
            split2s(a2, h, m); ph[2][j] = h; pm[2][j] = m;
        }
        size_t rb = (size_t)i * K3 + (size_t)(lane * 8);
        #pragma unroll
        for (int sec = 0; sec < 3; ++sec) {
            *(f16x8*)(Ah + rb + sec * 512) = ph[sec];
            *(f16x8*)(Am + rb + sec * 512) = pm[sec];
        }
    }
}

// ---------------- GEMM: out = tanh(A(M x 1536) * Bcat^T + (1+nc)*bias)
// fp16 2-plane x 2-plane, 3 products (hh -> accH0/accH1 by K-half; hm+mh -> accR1).
// 512 threads = 8 waves (2x4), wave tile 64x32, block tile 128x128, BK=64.
// m97 SINGLE-BUFFER structure: 4 planes x 16KB = 64KB LDS -> 2 blocks/CU
// (16 waves/CU at 128 VGPR). __launch_bounds__(512,2): the ",2" gives a
// 128-VGPR cap (",4" capped at 64 VGPR and spilled catastrophically in R5).
// LDS XOR swizzle (rule #21): linear LDS dest via global_load_lds,
// INVERSE-swizzled global source, swizzled ds_read.
__device__ __forceinline__ void stageTile(const char* gbase, _Float16* lds) {
    int tid = threadIdx.x;
    int wid = tid >> 6;
    #pragma unroll
    for (int rnd = 0; rnd < 2; ++rnd) {
        int c = rnd * 512 + tid;          // 16B chunk id within [128 rows][8 slots]
        int row = c >> 3;
        int gslot = (c & 7) ^ (row & 7);  // inverse swizzle on the SOURCE
        const void* gp = gbase + (size_t)row * (K3 * 2) + ((size_t)gslot << 4);
        _Float16* lp = lds + (size_t)(rnd * 512 + wid * 64) * 8;  // wave-uniform base
        __builtin_amdgcn_global_load_lds(
            (const __attribute__((address_space(1))) unsigned int*)gp,
            (__attribute__((address_space(3))) unsigned int*)lp, 16, 0, 0);
    }
}

__device__ __forceinline__ f32x4 mfma16(f16x8 a, f16x8 b, f32x4 c) {
    return __builtin_amdgcn_mfma_f32_16x16x32_f16(a, b, c, 0, 0, 0);
}

// one K-step's compute: interleaved per-kc {frag reads, MFMA}
__device__ __forceinline__ void compute_step(
    const _Float16* cAh, const _Float16* cAm, const _Float16* cBh, const _Float16* cBm,
    int wm, int wn, int l15, int koff0, int koff1,
    f32x4 (&accH)[4][2], f32x4 (&accR1)[4][2])
{
    #pragma unroll
    for (int kc = 0; kc < 2; ++kc) {
        int ko = kc ? koff1 : koff0;
        f16x8 ah[4], am[4], bh[2], bm[2];
        #pragma unroll
        for (int ni = 0; ni < 2; ++ni) {
            int co = (wn * 32 + ni * 16 + l15) * 64;
            bh[ni] = *(const f16x8*)&cBh[co + ko];
            bm[ni] = *(const f16x8*)&cBm[co + ko];
        }
        #pragma unroll
        for (int mi = 0; mi < 4; ++mi) {
            int ro = (wm * 64 + mi * 16 + l15) * 64;
            ah[mi] = *(const f16x8*)&cAh[ro + ko];
            am[mi] = *(const f16x8*)&cAm[ro + ko];
        }
        #pragma unroll
        for (int mi = 0; mi < 4; ++mi) {
            #pragma unroll
            for (int ni = 0; ni < 2; ++ni) {
                accH[mi][ni]  = mfma16(ah[mi], bh[ni], accH[mi][ni]);
                accR1[mi][ni] = mfma16(ah[mi], bm[ni], accR1[mi][ni]);
                accR1[mi][ni] = mfma16(am[mi], bh[ni], accR1[mi][ni]);
            }
        }
    }
}

__global__ __launch_bounds__(512, 2)
void k_gemm(const _Float16* __restrict__ Ah, const _Float16* __restrict__ Am,
            const _Float16* __restrict__ Bh, const _Float16* __restrict__ Bm,
            const float* __restrict__ bias, const int* __restrict__ counts,
            float* __restrict__ out, int Mreal, int row0) {
    __shared__ __align__(16) _Float16 sAh[128 * 64];
    __shared__ __align__(16) _Float16 sAm[128 * 64];
    __shared__ __align__(16) _Float16 sBh[128 * 64];
    __shared__ __align__(16) _Float16 sBm[128 * 64];

    // bijective XCD swizzle (m204)
    int nwg = gridDim.x, bid = blockIdx.x;
    int q = nwg >> 3, r = nwg & 7;
    int xcd = bid & 7, idx = bid >> 3;
    int wg = (xcd < r ? xcd * (q + 1) : r * (q + 1) + (xcd - r) * q) + idx;
    int panel = wg >> 2, colt = wg & 3;
    int m0 = panel * 128, n0 = colt * 128;

    int lane = threadIdx.x & 63, wid = threadIdx.x >> 6;
    int wm = wid >> 2, wn = wid & 3;
    int l15 = lane & 15, lg = lane >> 4, lx = lane & 7;

    const char* gAh = (const char*)(Ah + (size_t)m0 * K3);
    const char* gAm = (const char*)(Am + (size_t)m0 * K3);
    const char* gBh = (const char*)(Bh + (size_t)n0 * K3);
    const char* gBm = (const char*)(Bm + (size_t)n0 * K3);

    f32x4 accH0[4][2] = {};
    f32x4 accH1[4][2] = {};
    f32x4 accR1[4][2] = {};

    int koff0 = ((((0 << 2) + lg) ^ lx) << 3);
    int koff1 = ((((1 << 2) + lg) ^ lx) << 3);

    for (int t = 0; t < NT; ++t) {
        size_t kb = (size_t)t * 128;     // 64 elems * 2B along K
        stageTile(gAh + kb, sAh); stageTile(gAm + kb, sAm);
        stageTile(gBh + kb, sBh); stageTile(gBm + kb, sBm);
        __syncthreads();                 // vmcnt(0) drain hidden by co-resident block

        if (t < NT2)
            compute_step(sAh, sAm, sBh, sBm, wm, wn, l15, koff0, koff1, accH0, accR1);
        else
            compute_step(sAh, sAm, sBh, sBm, wm, wn, l15, koff0, koff1, accH1, accR1);

        __syncthreads();                 // reads done -> safe to overwrite
    }

    const float S1 = 1.0f / 2048.0f;        // 2^-11

    #pragma unroll
    for (int mi = 0; mi < 4; ++mi) {
        #pragma unroll
        for (int ni = 0; ni < 2; ++ni) {
            int colL = n0 + wn * 32 + ni * 16 + l15;
            #pragma unroll
            for (int rr = 0; rr < 4; ++rr) {
                int rowL = m0 + wm * 64 + mi * 16 + lg * 4 + rr;
                if (rowL < Mreal) {
                    int g = row0 + rowL;
                    float v = (accH0[mi][ni][rr] + accH1[mi][ni][rr])
                              + accR1[mi][ni][rr] * S1
                              + (1.0f + (float)counts[g]) * bias[colL];
                    out[(size_t)g * C_DIM + colL] = tanhf(v);
                }
            }
        }
    }
}

extern "C" void kernel_launch(void* const* d_in, const int* in_sizes, int n_in,
                              void* d_out, int out_size, void* d_ws, size_t ws_size,
                              hipStream_t stream) {
    const float* x    = (const float*)d_in[0];
    const float* Wt   = (const float*)d_in[1];
    const float* Wl   = (const float*)d_in[2];
    const float* Wr   = (const float*)d_in[3];
    const float* bias = (const float*)d_in[4];
    const int* parent = (const int*)d_in[5];
    const int* level  = (const int*)d_in[6];
    const int* pos    = (const int*)d_in[7];
    const int* sib    = (const int*)d_in[8];
    const int N = in_sizes[5];
    float* out = (float*)d_out;
    (void)n_in; (void)out_size;

    char* w = (char*)d_ws;
    size_t off = 0;
    auto alloc = [&](size_t bytes) -> void* {
        void* p = w + off;
        off += (bytes + 255) & ~(size_t)255;
        return p;
    };
    int* counts    = (int*)alloc((size_t)N * 4);
    int* starts    = (int*)alloc((size_t)N * 4);
    int* childlist = (int*)alloc((size_t)N * 4);
    int* bsums     = (int*)alloc(1024 * 4);
    _Float16* Bh   = (_Float16*)alloc((size_t)C_DIM * K3 * 2);
    _Float16* Bm   = (_Float16*)alloc((size_t)C_DIM * K3 * 2);

    size_t avail = ws_size > off ? ws_size - off : 0;
    long long Npad = ((long long)N + 127) & ~127LL;
    long long chunkM = (long long)(avail / ((size_t)K3 * 2 * 2)) & ~127LL;
    if (chunkM > Npad) chunkM = Npad;
    if (chunkM < 128) chunkM = 128;
    _Float16* Ah = (_Float16*)alloc((size_t)chunkM * K3 * 2);
    _Float16* Am = (_Float16*)alloc((size_t)chunkM * K3 * 2);

    hipMemsetAsync(counts, 0, (size_t)N * 4, stream);
    int nb256 = (N + 255) / 256;
    int nb1024 = (N + 1023) / 1024;
    k_count<<<nb256, 256, 0, stream>>>(parent, counts, N);
    k_scan1<<<nb1024, 1024, 0, stream>>>(counts, starts, bsums, N);
    k_scan2<<<1, 1024, 0, stream>>>(bsums, nb1024);
    k_scan3<<<nb1024, 1024, 0, stream>>>(starts, bsums, N);
    k_fill<<<nb256, 256, 0, stream>>>(parent, pos, starts, childlist, N);
    k_bcat<<<(C_DIM * K3 + 255) / 256, 256, 0, stream>>>(Wt, Wl, Wr, Bh, Bm);

    for (long long m0 = 0; m0 < N; m0 += chunkM) {
        int mc = (int)((N - m0 < chunkM) ? (N - m0) : chunkM);
        int mcPad = (mc + 127) & ~127;
        k_agg<<<2048, 256, 0, stream>>>(x, level, pos, sib, starts, counts, childlist,
                                        Ah, Am, (int)m0, mc);
        int ntiles = (mcPad / 128) * 4;
        k_gemm<<<ntiles, 512, 0, stream>>>(Ah, Am, Bh, Bm, bias, counts,
                                           out, mc, (int)m0);
    }
}

// Round 7
// 767.980 us; speedup vs baseline: 5.6625x; 1.4495x over previous
//
#include <hip/hip_runtime.h>
#include <hip/hip_bf16.h>
#include <stdint.h>

#define F_DIM 512
#define C_DIM 512
#define K3    1536   // 3 * F_DIM
#define NT    24     // K3 / 64

typedef _Float16 f16x8 __attribute__((ext_vector_type(8)));
typedef float    f32x4 __attribute__((ext_vector_type(4)));

__device__ __forceinline__ float rho_of(int p, int sb) {
    int d = sb - 1; if (d < 1) d = 1;
    return (float)(p - 1) / (float)d;
}

// 2-way fp16 split with exact pow2 plane scaling: v ~= h + m*2^-11
// (m plane scaled into normal fp16 range; residual ~2^-24*|v|)
__device__ __forceinline__ void split2s(float v, _Float16& h, _Float16& m) {
    h = (_Float16)v;
    float r1 = v - (float)h;          // exact
    m = (_Float16)(r1 * 2048.0f);     // scale exact, one rounding
}

// ---------------- CSR build ----------------
__global__ void k_count(const int* __restrict__ parent, int* __restrict__ counts, int n) {
    int c = blockIdx.x * 256 + threadIdx.x;
    if (c >= 1 && c < n) atomicAdd(&counts[parent[c]], 1);
}

__device__ __forceinline__ int blockScanIncl(int v, int* sm) {
    int lane = threadIdx.x & 63;
    int w = threadIdx.x >> 6;
    #pragma unroll
    for (int d = 1; d < 64; d <<= 1) {
        int t = __shfl_up(v, d, 64);
        if (lane >= d) v += t;
    }
    if (lane == 63) sm[w] = v;
    __syncthreads();
    if (threadIdx.x < 64) {
        int s = (threadIdx.x < 16) ? sm[threadIdx.x] : 0;
        #pragma unroll
        for (int d = 1; d < 16; d <<= 1) {
            int t = __shfl_up(s, d, 64);
            if (lane >= d) s += t;
        }
        if (threadIdx.x < 16) sm[threadIdx.x] = s;
    }
    __syncthreads();
    return v + (w > 0 ? sm[w - 1] : 0);
}

__global__ void k_scan1(const int* __restrict__ counts, int* __restrict__ starts,
                        int* __restrict__ bsums, int n) {
    __shared__ int sm[16];
    int i = blockIdx.x * 1024 + threadIdx.x;
    int v = (i < n) ? counts[i] : 0;
    int incl = blockScanIncl(v, sm);
    if (i < n) starts[i] = incl - v;
    if (threadIdx.x == 1023) bsums[blockIdx.x] = incl;
}

__global__ void k_scan2(int* __restrict__ bsums, int nb) {
    __shared__ int sm[16];
    int v = ((int)threadIdx.x < nb) ? bsums[threadIdx.x] : 0;
    int incl = blockScanIncl(v, sm);
    if ((int)threadIdx.x < nb) bsums[threadIdx.x] = incl - v;  // exclusive
}

__global__ void k_scan3(int* __restrict__ starts, const int* __restrict__ bsums, int n) {
    int i = blockIdx.x * 1024 + threadIdx.x;
    if (i < n) starts[i] += bsums[blockIdx.x];
}

__global__ void k_fill(const int* __restrict__ parent, const int* __restrict__ pos,
                       const int* __restrict__ starts, int* __restrict__ childlist, int n) {
    int c = blockIdx.x * 256 + threadIdx.x;
    if (c >= 1 && c < n) childlist[starts[parent[c]] + pos[c]] = c;
}

// ---------------- B concat + 2-way split:  B[j][sec*512+f], sec: 0=Wt 1=Wl 2=Wr
__global__ void k_bcat(const float* __restrict__ Wt, const float* __restrict__ Wl,
                       const float* __restrict__ Wr,
                       _Float16* __restrict__ Bh, _Float16* __restrict__ Bm) {
    int i = blockIdx.x * 256 + threadIdx.x;
    if (i >= C_DIM * K3) return;
    int j = i / K3, kk = i - j * K3;
    int sec = kk >> 9, f = kk & 511;
    const float* W = (sec == 0) ? Wt : ((sec == 1) ? Wl : Wr);
    float v = W[j * F_DIM + f];
    _Float16 h, m;
    split2s(v, h, m);
    Bh[i] = h; Bm[i] = m;
}

// ---------------- aggregation: one wave per node.
// S0 = sum of x over {self + children}, S1 = sum of rho*x.
// A row = [ t*S0 | u*S0 - u*u*S1 | u*S1 ]  -> 2-way split planes.
__global__ __launch_bounds__(256)
void k_agg(const float* __restrict__ x, const int* __restrict__ level,
           const int* __restrict__ pos, const int* __restrict__ sib,
           const int* __restrict__ starts, const int* __restrict__ counts,
           const int* __restrict__ childlist,
           _Float16* __restrict__ Ah, _Float16* __restrict__ Am,
           int node0, int cnt) {
    int lane = threadIdx.x & 63;
    int gw = (blockIdx.x * 256 + threadIdx.x) >> 6;
    int nW = (gridDim.x * 256) >> 6;
    for (int i = gw; i < cnt; i += nW) {
        int s = node0 + i;
        float t = 0.5f * (float)level[s];
        float u = 1.0f - t;
        float u2 = u * u;
        float s0[8], s1[8];
        #pragma unroll
        for (int j = 0; j < 8; ++j) { s0[j] = 0.f; s1[j] = 0.f; }
        {
            float r = rho_of(pos[s], sib[s]);
            const float4* xp = (const float4*)(x + (size_t)s * F_DIM) + lane * 2;
            float4 a = xp[0], b = xp[1];
            float vv[8] = {a.x, a.y, a.z, a.w, b.x, b.y, b.z, b.w};
            #pragma unroll
            for (int j = 0; j < 8; ++j) { s0[j] += vv[j]; s1[j] = fmaf(r, vv[j], s1[j]); }
        }
        int cs = starts[s], ne = counts[s];
        for (int e = 0; e < ne; ++e) {
            int c = childlist[cs + e];
            float r = rho_of(pos[c], sib[c]);
            const float4* xp = (const float4*)(x + (size_t)c * F_DIM) + lane * 2;
            float4 a = xp[0], b = xp[1];
            float vv[8] = {a.x, a.y, a.z, a.w, b.x, b.y, b.z, b.w};
            #pragma unroll
            for (int j = 0; j < 8; ++j) { s0[j] += vv[j]; s1[j] = fmaf(r, vv[j], s1[j]); }
        }
        f16x8 ph[3], pm[3];
        #pragma unroll
        for (int j = 0; j < 8; ++j) {
            float a0 = t * s0[j];
            float a1 = fmaf(-u2, s1[j], u * s0[j]);
            float a2 = u * s1[j];
            _Float16 h, m;
            split2s(a0, h, m); ph[0][j] = h; pm[0][j] = m;
            split2s(a1, h, m); ph[1][j] = h; pm[1][j] = m;
            split2s(a2, h, m); ph[2][j] = h; pm[2][j] = m;
        }
        size_t rb = (size_t)i * K3 + (size_t)(lane * 8);
        #pragma unroll
        for (int sec = 0; sec < 3; ++sec) {
            *(f16x8*)(Ah + rb + sec * 512) = ph[sec];
            *(f16x8*)(Am + rb + sec * 512) = pm[sec];
        }
    }
}

// ---------------- GEMM: out = tanh(A(M x 1536) * Bcat^T + (1+nc)*bias)
// fp16 2-plane x 2-plane, 3 products (hh -> accH; hm+mh -> accR).
// 256 threads = 4 waves (2x2), wave tile 64x64, block tile 128x128, BK=64.
// TWO independent blocks per CU (m114 implicit overlap): per-lane regs
// acc 128 (AGPR) + frags 64 + addr ~40 <= 256 -> 2 waves/SIMD = 2 blocks;
// LDS 64KB x 2 = 128KB <= 160KB. One block's compute hides the other
// block's stage+barrier drain — the verified m97 mechanism at 128^2 tile.
// LDS XOR swizzle (rule #21): linear LDS dest via global_load_lds,
// INVERSE-swizzled global source, swizzled ds_read.
__device__ __forceinline__ void stageTile(const char* gbase, _Float16* lds) {
    int tid = threadIdx.x;
    int wid = tid >> 6;
    #pragma unroll
    for (int rnd = 0; rnd < 4; ++rnd) {
        int c = rnd * 256 + tid;          // 16B chunk id within [128 rows][8 slots]
        int row = c >> 3;
        int gslot = (c & 7) ^ (row & 7);  // inverse swizzle on the SOURCE
        const void* gp = gbase + (size_t)row * (K3 * 2) + ((size_t)gslot << 4);
        _Float16* lp = lds + (size_t)(rnd * 256 + wid * 64) * 8;  // wave-uniform base
        __builtin_amdgcn_global_load_lds(
            (const __attribute__((address_space(1))) unsigned int*)gp,
            (__attribute__((address_space(3))) unsigned int*)lp, 16, 0, 0);
    }
}

__device__ __forceinline__ f32x4 mfma16(f16x8 a, f16x8 b, f32x4 c) {
    return __builtin_amdgcn_mfma_f32_16x16x32_f16(a, b, c, 0, 0, 0);
}

// one K-step's compute: per kc {frag reads, 48 MFMA}
__device__ __forceinline__ void compute_step(
    const _Float16* cAh, const _Float16* cAm, const _Float16* cBh, const _Float16* cBm,
    int wm, int wn, int l15, int koff0, int koff1,
    f32x4 (&accH)[4][4], f32x4 (&accR)[4][4])
{
    #pragma unroll
    for (int kc = 0; kc < 2; ++kc) {
        int ko = kc ? koff1 : koff0;
        f16x8 ah[4], am[4], bh[4], bm[4];
        #pragma unroll
        for (int ni = 0; ni < 4; ++ni) {
            int co = (wn * 64 + ni * 16 + l15) * 64;
            bh[ni] = *(const f16x8*)&cBh[co + ko];
            bm[ni] = *(const f16x8*)&cBm[co + ko];
        }
        #pragma unroll
        for (int mi = 0; mi < 4; ++mi) {
            int ro = (wm * 64 + mi * 16 + l15) * 64;
            ah[mi] = *(const f16x8*)&cAh[ro + ko];
            am[mi] = *(const f16x8*)&cAm[ro + ko];
        }
        #pragma unroll
        for (int mi = 0; mi < 4; ++mi) {
            #pragma unroll
            for (int ni = 0; ni < 4; ++ni) {
                accH[mi][ni] = mfma16(ah[mi], bh[ni], accH[mi][ni]);
                accR[mi][ni] = mfma16(ah[mi], bm[ni], accR[mi][ni]);
                accR[mi][ni] = mfma16(am[mi], bh[ni], accR[mi][ni]);
            }
        }
    }
}

__global__ __launch_bounds__(256, 2)
void k_gemm(const _Float16* __restrict__ Ah, const _Float16* __restrict__ Am,
            const _Float16* __restrict__ Bh, const _Float16* __restrict__ Bm,
            const float* __restrict__ bias, const int* __restrict__ counts,
            float* __restrict__ out, int Mreal, int row0) {
    __shared__ __align__(16) _Float16 sAh[128 * 64];
    __shared__ __align__(16) _Float16 sAm[128 * 64];
    __shared__ __align__(16) _Float16 sBh[128 * 64];
    __shared__ __align__(16) _Float16 sBm[128 * 64];

    // bijective XCD swizzle (m204)
    int nwg = gridDim.x, bid = blockIdx.x;
    int q = nwg >> 3, r = nwg & 7;
    int xcd = bid & 7, idx = bid >> 3;
    int wg = (xcd < r ? xcd * (q + 1) : r * (q + 1) + (xcd - r) * q) + idx;
    int panel = wg >> 2, colt = wg & 3;
    int m0 = panel * 128, n0 = colt * 128;

    int lane = threadIdx.x & 63, wid = threadIdx.x >> 6;
    int wm = wid >> 1, wn = wid & 1;
    int l15 = lane & 15, lg = lane >> 4, lx = lane & 7;

    const char* gAh = (const char*)(Ah + (size_t)m0 * K3);
    const char* gAm = (const char*)(Am + (size_t)m0 * K3);
    const char* gBh = (const char*)(Bh + (size_t)n0 * K3);
    const char* gBm = (const char*)(Bm + (size_t)n0 * K3);

    f32x4 accH[4][4] = {};
    f32x4 accR[4][4] = {};

    int koff0 = ((((0 << 2) + lg) ^ lx) << 3);
    int koff1 = ((((1 << 2) + lg) ^ lx) << 3);

    for (int t = 0; t < NT; ++t) {
        size_t kb = (size_t)t * 128;     // 64 elems * 2B along K
        stageTile(gAh + kb, sAh); stageTile(gAm + kb, sAm);
        stageTile(gBh + kb, sBh); stageTile(gBm + kb, sBm);
        __syncthreads();                 // drain hidden by co-resident block

        compute_step(sAh, sAm, sBh, sBm, wm, wn, l15, koff0, koff1, accH, accR);

        __syncthreads();                 // reads done -> safe to overwrite
    }

    const float S1 = 1.0f / 2048.0f;        // 2^-11

    #pragma unroll
    for (int mi = 0; mi < 4; ++mi) {
        #pragma unroll
        for (int ni = 0; ni < 4; ++ni) {
            int colL = n0 + wn * 64 + ni * 16 + l15;
            #pragma unroll
            for (int rr = 0; rr < 4; ++rr) {
                int rowL = m0 + wm * 64 + mi * 16 + lg * 4 + rr;
                if (rowL < Mreal) {
                    int g = row0 + rowL;
                    float v = accH[mi][ni][rr]
                              + accR[mi][ni][rr] * S1
                              + (1.0f + (float)counts[g]) * bias[colL];
                    out[(size_t)g * C_DIM + colL] = tanhf(v);
                }
            }
        }
    }
}

extern "C" void kernel_launch(void* const* d_in, const int* in_sizes, int n_in,
                              void* d_out, int out_size, void* d_ws, size_t ws_size,
                              hipStream_t stream) {
    const float* x    = (const float*)d_in[0];
    const float* Wt   = (const float*)d_in[1];
    const float* Wl   = (const float*)d_in[2];
    const float* Wr   = (const float*)d_in[3];
    const float* bias = (const float*)d_in[4];
    const int* parent = (const int*)d_in[5];
    const int* level  = (const int*)d_in[6];
    const int* pos    = (const int*)d_in[7];
    const int* sib    = (const int*)d_in[8];
    const int N = in_sizes[5];
    float* out = (float*)d_out;
    (void)n_in; (void)out_size;

    char* w = (char*)d_ws;
    size_t off = 0;
    auto alloc = [&](size_t bytes) -> void* {
        void* p = w + off;
        off += (bytes + 255) & ~(size_t)255;
        return p;
    };
    int* counts    = (int*)alloc((size_t)N * 4);
    int* starts    = (int*)alloc((size_t)N * 4);
    int* childlist = (int*)alloc((size_t)N * 4);
    int* bsums     = (int*)alloc(1024 * 4);
    _Float16* Bh   = (_Float16*)alloc((size_t)C_DIM * K3 * 2);
    _Float16* Bm   = (_Float16*)alloc((size_t)C_DIM * K3 * 2);

    size_t avail = ws_size > off ? ws_size - off : 0;
    long long Npad = ((long long)N + 127) & ~127LL;
    long long chunkM = (long long)(avail / ((size_t)K3 * 2 * 2)) & ~127LL;
    if (chunkM > Npad) chunkM = Npad;
    if (chunkM < 128) chunkM = 128;
    _Float16* Ah = (_Float16*)alloc((size_t)chunkM * K3 * 2);
    _Float16* Am = (_Float16*)alloc((size_t)chunkM * K3 * 2);

    hipMemsetAsync(counts, 0, (size_t)N * 4, stream);
    int nb256 = (N + 255) / 256;
    int nb1024 = (N + 1023) / 1024;
    k_count<<<nb256, 256, 0, stream>>>(parent, counts, N);
    k_scan1<<<nb1024, 1024, 0, stream>>>(counts, starts, bsums, N);
    k_scan2<<<1, 1024, 0, stream>>>(bsums, nb1024);
    k_scan3<<<nb1024, 1024, 0, stream>>>(starts, bsums, N);
    k_fill<<<nb256, 256, 0, stream>>>(parent, pos, starts, childlist, N);
    k_bcat<<<(C_DIM * K3 + 255) / 256, 256, 0, stream>>>(Wt, Wl, Wr, Bh, Bm);

    for (long long m0 = 0; m0 < N; m0 += chunkM) {
        int mc = (int)((N - m0 < chunkM) ? (N - m0) : chunkM);
        int mcPad = (mc + 127) & ~127;
        k_agg<<<2048, 256, 0, stream>>>(x, level, pos, sib, starts, counts, childlist,
                                        Ah, Am, (int)m0, mc);
        int ntiles = (mcPad / 128) * 4;
        k_gemm<<<ntiles, 256, 0, stream>>>(Ah, Am, Bh, Bm, bias, counts,
                                           out, mc, (int)m0);
    }
}